// Round 9
// baseline (125.052 us; speedup 1.0000x reference)
//
#include <hip/hip_runtime.h>
#include <hip/hip_bf16.h>

typedef __bf16 bf16x8 __attribute__((ext_vector_type(8)));
typedef float  f32x16 __attribute__((ext_vector_type(16)));
typedef float  f4     __attribute__((ext_vector_type(4)));
typedef unsigned short us4 __attribute__((ext_vector_type(4)));
typedef unsigned short us8 __attribute__((ext_vector_type(8)));

__device__ inline unsigned short f2bf(float f) {
  union { float f; unsigned int u; } v; v.f = f;
  unsigned int r = v.u + 0x7fffu + ((v.u >> 16) & 1u);
  return (unsigned short)(r >> 16);
}
__device__ inline float bf2f(unsigned short u) {
  union { unsigned int u; float f; } v; v.u = (unsigned int)u << 16;
  return v.f;
}

__device__ inline void gload_lds16(const void* g, void* l) {
  __builtin_amdgcn_global_load_lds((const __attribute__((address_space(1))) void*)g,
                                   (__attribute__((address_space(3))) void*)l, 16, 0, 0);
}

// ------- fused: fp32->bf16 convert of x  +  W transpose/concat to bf16 -------
__global__ __launch_bounds__(256) void convfused(const float* __restrict__ x,
                                                 const float* __restrict__ Wq,
                                                 const float* __restrict__ Wk,
                                                 const float* __restrict__ Wv,
                                                 unsigned short* __restrict__ xb,
                                                 unsigned short* __restrict__ wt) {
  __shared__ unsigned short tile[32][33];
  if (blockIdx.x < 3072) {
    int i = blockIdx.x * 256 + threadIdx.x;       // indexes float4
    f4 v = ((const f4*)x)[i];
    us4 o;
    #pragma unroll
    for (int c = 0; c < 4; ++c) o[c] = f2bf(v[c]);
    ((us4*)xb)[i] = o;
  } else {
    int b = blockIdx.x - 3072;                    // 0..1727 = 3 * 24 * 24
    int bz = b / 576, rem = b % 576;
    int bx = rem / 24, by = rem % 24;
    const float* W = bz == 0 ? Wq : (bz == 1 ? Wk : Wv);
    int k0 = bx * 32, n0 = by * 32;
    int c = threadIdx.x & 31, r8 = threadIdx.x >> 5;
    #pragma unroll
    for (int p = 0; p < 4; ++p) {
      int r = p * 8 + r8;
      tile[r][c] = f2bf(W[(size_t)(k0 + r) * 768 + n0 + c]);
    }
    __syncthreads();
    #pragma unroll
    for (int p = 0; p < 4; ++p) {
      int r = p * 8 + r8;  // n index
      wt[((size_t)bz * 768 + n0 + r) * 768 + k0 + c] = tile[c][r];
    }
  }
}

// ------- V columns of QKV -> Vt[768][4096] bf16 -------
__global__ __launch_bounds__(256) void transv(const unsigned short* __restrict__ qkv,
                                              unsigned short* __restrict__ vt) {
  __shared__ unsigned short tile[32][33];
  int s0 = blockIdx.x * 32, d0 = blockIdx.y * 32;
  int c = threadIdx.x & 31, r8 = threadIdx.x >> 5;
  #pragma unroll
  for (int p = 0; p < 4; ++p) {
    int r = p * 8 + r8;  // s index
    tile[r][c] = qkv[(size_t)(s0 + r) * 2304 + 1536 + d0 + c];
  }
  __syncthreads();
  #pragma unroll
  for (int p = 0; p < 4; ++p) {
    int r = p * 8 + r8;  // d index
    vt[(size_t)(d0 + r) * 4096 + s0 + c] = tile[c][r];
  }
}

// ======== deep-pipelined bf16 GEMM, 32x32x16 MFMA, ring-4 K32 slots ========
// BM = BN = WAVES*32, threads = WAVES*64 (staging invariant: threads == BM+BN).
// Per-wave C: (MB*32) x (NB*32), MB=WAVES/WM, NB=WAVES/WN, acc f32x16 per 32x32 frag.
// Per K32-step: counted vmcnt -> barrier -> stage slot (s+3)&3 -> ds_read frags
// (MB*2 + NB*2 x b128) -> 16 MFMA (kk-chained pairs). RA=true adds register
// read-ahead: prefetch next step's frags into the alternate named set (rule #20),
// vmcnt tightens 8->4 (slot s+1 must have landed for the prefetch).
// Hazards (both paths): stage(s) writes slot (s-1)&3, last read at step s-2,
// ordered by the step-s barrier; vmcnt+barrier pairs make staged data visible
// to all waves (each wave waits its own loads, barrier collectivizes).
// LDS swizzle: element (row,k) at byte (row*64 + k*2) ^ ((row_bit3)<<5); staging
// pre-swizzles the GLOBAL source k so linear global_load_lds lands swizzled.
// 32x32x16 layouts: A lane l -> row l&31, k (l>>5)*8+j; C/D: col=l&31,
// row=(reg&3)+8*(reg>>2)+4*(l>>5)  [measured m74/m101].
// DOEXP: epilogue v = exp(v*cscale). DOSCALE: epilogue v *= rowinv[r].
// Split-K: gridDim.y slice y computes K range [y*kspan,(y+1)*kspan) -> C0/C1.
template <int WAVES, int WM, int WN, int MINW, bool RA, typename OUT_T, bool DOEXP, bool DOSCALE>
__global__ __launch_bounds__(WAVES * 64, MINW) void gemmdp(const unsigned short* __restrict__ A,
                                                           const unsigned short* __restrict__ B,
                                                           OUT_T* __restrict__ C0,
                                                           OUT_T* __restrict__ C1,
                                                           const float* __restrict__ rowinv,
                                                           int lda, int ldb, int ldc, int kspan,
                                                           int nbx, float cscale) {
  constexpr int BM = WAVES * 32, BN = WAVES * 32;
  constexpr int MB = WAVES / WM, NB = WAVES / WN;   // 32x32 blocks per wave
  constexpr int SLOT = (BM + BN) * 64;
  __shared__ __align__(16) char lds[4 * SLOT];
  const int tid = threadIdx.x;
  const int w = tid >> 6, l = tid & 63;
  const int wr = w / WN, wc = w % WN;
  const int l31 = l & 31, lh = l >> 5;

  const int nwg = gridDim.x;             // bijective XCD swizzle (nwg % 8 == 0)
  const int swz = (blockIdx.x & 7) * (nwg >> 3) + (blockIdx.x >> 3);
  const int bx = swz % nbx, by = swz / nbx;
  const int m0 = by * BM, n0 = bx * BN;
  const int koff0 = blockIdx.y * kspan;
  OUT_T* __restrict__ C = blockIdx.y ? C1 : C0;

  f32x16 acc[MB][NB] = {};

  // --- staging: thread covers 4x 16B chunks (A rows trow, trow+BM/2; B same) ---
  const int trow = tid >> 2;
  const int koff = ((tid & 3) * 8) ^ (((tid >> 5) & 1) * 16);  // inverse-swizzled source k
  const unsigned short* gA0 = A + (size_t)(m0 + trow) * lda + koff + koff0;
  const unsigned short* gA1 = A + (size_t)(m0 + BM / 2 + trow) * lda + koff + koff0;
  const unsigned short* gB0 = B + (size_t)(n0 + trow) * ldb + koff + koff0;
  const unsigned short* gB1 = B + (size_t)(n0 + BN / 2 + trow) * ldb + koff + koff0;
  const int wave16 = (tid & ~63) * 16;   // wave-uniform LDS chunk base

  auto stage = [&](int slot, int k0) {
    char* base = lds + slot * SLOT;
    gload_lds16(gA0 + k0, base + wave16);
    gload_lds16(gA1 + k0, base + BM * 32 + wave16);
    gload_lds16(gB0 + k0, base + BM * 64 + wave16);
    gload_lds16(gB1 + k0, base + BM * 64 + BN * 32 + wave16);
  };

  // --- fragment read offsets; xor bit5 by row bit3 (= l bit3) ---
  const int xorv = ((l >> 3) & 1) << 5;
  const int aoff = (wr * (MB * 32) + l31) * 64 + lh * 16;            // + mb*2048 + kk*32
  const int boff = BM * 64 + (wc * (NB * 32) + l31) * 64 + lh * 16;  // + nb*2048 + kk*32

  auto ldfrags = [&](int slot, bf16x8 (&pa)[MB * 2], bf16x8 (&pb)[NB * 2]) {
    const char* sb = lds + slot * SLOT;
    #pragma unroll
    for (int mb = 0; mb < MB; ++mb)
      #pragma unroll
      for (int kk = 0; kk < 2; ++kk)
        pa[mb * 2 + kk] = *(const bf16x8*)(sb + ((aoff + mb * 2048 + kk * 32) ^ xorv));
    #pragma unroll
    for (int nb = 0; nb < NB; ++nb)
      #pragma unroll
      for (int kk = 0; kk < 2; ++kk)
        pb[nb * 2 + kk] = *(const bf16x8*)(sb + ((boff + nb * 2048 + kk * 32) ^ xorv));
  };

  auto domfma = [&](bf16x8 (&ca)[MB * 2], bf16x8 (&cb)[NB * 2]) {
    __builtin_amdgcn_s_setprio(1);
    #pragma unroll
    for (int kk = 0; kk < 2; ++kk)
      #pragma unroll
      for (int mb = 0; mb < MB; ++mb)
        #pragma unroll
        for (int nb = 0; nb < NB; ++nb)
          acc[mb][nb] = __builtin_amdgcn_mfma_f32_32x32x16_bf16(
              ca[mb * 2 + kk], cb[nb * 2 + kk], acc[mb][nb], 0, 0, 0);
    __builtin_amdgcn_s_setprio(0);
  };

  const int nsteps = kspan >> 5;         // even by construction

  if constexpr (RA) {
    bf16x8 fa[MB * 2], fb[NB * 2], ga[MB * 2], gb[NB * 2];
    stage(0, 0); stage(1, 32); stage(2, 64);
    asm volatile("s_waitcnt vmcnt(8)" ::: "memory");   // slot 0 landed (own wave)
    __builtin_amdgcn_s_barrier();                      // slot 0 landed (all waves)
    ldfrags(0, fa, fb);

    auto step = [&](int s, bf16x8 (&ca)[MB * 2], bf16x8 (&cb)[NB * 2],
                    bf16x8 (&xa)[MB * 2], bf16x8 (&xb2)[NB * 2]) {
      __builtin_amdgcn_sched_barrier(0);
      if (s < nsteps - 2) asm volatile("s_waitcnt vmcnt(4)" ::: "memory");
      else                asm volatile("s_waitcnt vmcnt(0)" ::: "memory");
      __builtin_amdgcn_s_barrier();
      __builtin_amdgcn_sched_barrier(0);
      if (s + 3 < nsteps) stage((s + 3) & 3, (s + 3) << 5);
      if (s + 1 < nsteps) ldfrags((s + 1) & 3, xa, xb2);
      domfma(ca, cb);
    };
    for (int s = 0; s < nsteps; s += 2) {
      step(s,     fa, fb, ga, gb);
      step(s + 1, ga, gb, fa, fb);
    }
  } else {
    bf16x8 fa[MB * 2], fb[NB * 2];
    stage(0, 0); stage(1, 32); stage(2, 64);
    for (int s = 0; s < nsteps; ++s) {
      __builtin_amdgcn_sched_barrier(0);
      if (s < nsteps - 2)       asm volatile("s_waitcnt vmcnt(8)" ::: "memory");
      else if (s == nsteps - 2) asm volatile("s_waitcnt vmcnt(4)" ::: "memory");
      else                      asm volatile("s_waitcnt vmcnt(0)" ::: "memory");
      __builtin_amdgcn_s_barrier();
      __builtin_amdgcn_sched_barrier(0);
      if (s + 3 < nsteps) stage((s + 3) & 3, (s + 3) << 5);
      ldfrags(s & 3, fa, fb);
      domfma(fa, fb);
    }
  }

  #pragma unroll
  for (int mb = 0; mb < MB; ++mb)
    #pragma unroll
    for (int nb = 0; nb < NB; ++nb) {
      int colg = n0 + wc * (NB * 32) + nb * 32 + l31;
      int rbase = m0 + wr * (MB * 32) + mb * 32 + 4 * lh;
      #pragma unroll
      for (int reg = 0; reg < 16; ++reg) {
        int r = rbase + (reg & 3) + 8 * (reg >> 2);
        float v = acc[mb][nb][reg] * cscale;
        if constexpr (DOEXP)   v = __expf(v);
        if constexpr (DOSCALE) v *= rowinv[r];
        if constexpr (__is_same(OUT_T, unsigned short)) C[(size_t)r * ldc + colg] = f2bf(v);
        else                                            C[(size_t)r * ldc + colg] = v;
      }
    }
}

// ------- rowinv[r] = 1 / sum(P[r][:]) ; P bf16 [4096][4096], one wave per row -------
__global__ __launch_bounds__(256) void rowsum(const unsigned short* __restrict__ P,
                                              float* __restrict__ rowinv) {
  const int wv = threadIdx.x >> 6, l = threadIdx.x & 63;
  const int r = blockIdx.x * 4 + wv;
  const unsigned short* row = P + (size_t)r * 4096;
  float sum = 0.f;
  #pragma unroll
  for (int j = 0; j < 8; ++j) {
    us8 v = ((const us8*)row)[l + j * 64];
    #pragma unroll
    for (int c = 0; c < 8; ++c) sum += bf2f(v[c]);
  }
  #pragma unroll
  for (int o = 32; o > 0; o >>= 1) sum += __shfl_xor(sum, o);
  if (l == 0) rowinv[r] = 1.f / sum;
}

// ------- out += p1 (f4 elementwise) -------
__global__ __launch_bounds__(256) void reduce_add(float* __restrict__ out,
                                                  const float* __restrict__ p1) {
  int i = blockIdx.x * 256 + threadIdx.x;
  f4 a = ((const f4*)out)[i];
  f4 b = ((const f4*)p1)[i];
  #pragma unroll
  for (int c = 0; c < 4; ++c) a[c] += b[c];
  ((f4*)out)[i] = a;
}

extern "C" void kernel_launch(void* const* d_in, const int* in_sizes, int n_in,
                              void* d_out, int out_size, void* d_ws, size_t ws_size,
                              hipStream_t stream) {
  const float* x  = (const float*)d_in[0];
  const float* Wq = (const float*)d_in[1];
  const float* Wk = (const float*)d_in[2];
  const float* Wv = (const float*)d_in[3];
  float* out = (float*)d_out;
  char* ws = (char*)d_ws;

  // ws layout (bytes):
  //   [0, 18874368)            qkv bf16 [4096][2304]; dead after QK gemm ->
  //                            reused as PV split-K partial p1 fp32 [4096][768]
  //   [18874368, 52428800)     P bf16 [4096][4096] (unnormalized exp(scores))
  //       xb (6.3MB) and wt (3.5MB) alias this region; both dead before QK writes P
  //   [52428800, 58720256)     Vt bf16 [768][4096]
  //   [58720256, 58736640)     rowinv fp32 [4096]
  unsigned short* qkv = (unsigned short*)ws;
  unsigned short* P   = (unsigned short*)(ws + 18874368);
  unsigned short* xb  = (unsigned short*)(ws + 18874368);
  unsigned short* wt  = (unsigned short*)(ws + 18874368 + 6291456);
  unsigned short* vt  = (unsigned short*)(ws + 52428800);
  float* rowinvp      = (float*)(ws + 58720256);
  float* p1           = (float*)ws;                    // aliases qkv (dead by then)

  const float qscale = 0.03608439182435161f;  // 1/sqrt(768)

  convfused<<<4800, 256, 0, stream>>>(x, Wq, Wk, Wv, xb, wt);
  // QKV = x @ [Wq|Wk|Wv]   (M=4096, N=2304, K=768), 128x128 -> 576 blocks, ring-4+RA
  gemmdp<4, 2, 2, 2, true, unsigned short, false, false><<<576, 256, 0, stream>>>(
      xb, wt, qkv, qkv, nullptr, 768, 768, 2304, 768, 18, 1.0f);
  transv<<<dim3(128, 24), 256, 0, stream>>>(qkv, vt);
  // P = exp((Q @ K^T) * qscale)  (M=4096, N=4096, K=768), 256x256 -> 256 blocks, ring-4 no-RA
  gemmdp<8, 2, 4, 2, false, unsigned short, true, false><<<256, 512, 0, stream>>>(
      qkv, qkv + 768, P, P, nullptr, 2304, 2304, 4096, 768, 16, qscale);
  // rowinv = 1 / row-sums of P
  rowsum<<<1024, 256, 0, stream>>>(P, rowinvp);
  // out = (P @ V) * rowinv (M=4096, N=768, K=4096), 128x128, split-K=2, ring-4+RA
  gemmdp<4, 2, 2, 2, true, float, false, true><<<dim3(192, 2), 256, 0, stream>>>(
      P, vt, out, p1, rowinvp, 4096, 4096, 768, 2048, 6, 1.0f);
  reduce_add<<<3072, 256, 0, stream>>>(out, p1);
}